// Round 1
// baseline (1006.397 us; speedup 1.0000x reference)
//
#include <hip/hip_runtime.h>
#include <hip/hip_bf16.h>
#include <cstdint>

static constexpr int NN = 100000;     // nodes
static constexpr int NE = 800000;     // edges (without self loops)
static constexpr int EP = NE + NN;    // edges incl. self loops
static constexpr int NB = (NN + 255) / 256;  // scan blocks

typedef unsigned short ushort;
typedef __attribute__((ext_vector_type(8))) short short8;
typedef __attribute__((ext_vector_type(8))) ushort ushort8v;
typedef __attribute__((ext_vector_type(4))) ushort ushort4v;
typedef __attribute__((ext_vector_type(4))) float f32x4;

__device__ __forceinline__ float leaky(float x) { return x > 0.f ? x : 0.2f * x; }

// float -> bf16 bits (RNE)
__device__ __forceinline__ ushort f2bf(float f) {
    unsigned int u = __float_as_uint(f);
    u += 0x7fffu + ((u >> 16) & 1u);
    return (ushort)(u >> 16);
}
__device__ __forceinline__ float bf2f(ushort h) {
    return __uint_as_float(((unsigned int)h) << 16);
}

// ---------------------------------------------------------------------------
// Weight pre-tiling: W (virtual concat [Wa | Wb], K x NT, row-major) ->
//   Whi/Wlo: [K/32][NT][32] bf16 (hi + lo split).  Tiny, runs once per layer.
// ---------------------------------------------------------------------------
__global__ void pretile_kernel(const float* __restrict__ Wa, const float* __restrict__ Wb,
                               int K, int CS, int NT,
                               ushort* __restrict__ Whi, ushort* __restrict__ Wlo)
{
    int idx = blockIdx.x * 256 + threadIdx.x;
    if (idx >= K * NT) return;
    int k = idx / NT, c = idx - k * NT;
    float v = (c < CS) ? Wa[(size_t)k * CS + c] : Wb[(size_t)k * (NT - CS) + (c - CS)];
    ushort h = f2bf(v);
    ushort l = f2bf(v - bf2f(h));
    size_t o = ((size_t)(k >> 5) * NT + c) * 32 + (k & 31);
    Whi[o] = h; Wlo[o] = l;
}

// ---------------------------------------------------------------------------
// Split-bf16 MFMA GEMM (3-pass hi/lo emulation, fp32-grade accuracy).
//   Y = X @ W, X = virtual concat of up to 3 sources split at K1,K2.
//   W pre-tiled as Wthi/Wtlo [K/32][NTOT][32] bf16.
//   Block: 256 thr (4 waves, 2x2), tile 128 rows x NTOT cols, full N per block.
//   bias[c-BIAS_OFF] added to cols >= BIAS_OFF; Y split at CSPLIT into Y1/Y2.
//   Attention-logit epilogue for cols < ATTN (heads of width ACC).
// MFMA 16x16x32 bf16 layouts (m89/m91-verified):
//   A: lane l holds A[l&15][8*(l>>4)+e]; B: lane l holds B[8*(l>>4)+e][l&15]
//   D: lane l reg r = D[(l>>4)*4+r][l&15]
// ---------------------------------------------------------------------------
template<int KTOT, int NTOT, int K1, int K2, int CSPLIT, int BIAS_OFF,
         int AHH, int ACC, int ATTN>
__global__ __launch_bounds__(256)
void gemm_mfma(const float* __restrict__ X1, const float* __restrict__ X2,
               const float* __restrict__ X3, int ldx1, int ldx2, int ldx3,
               const ushort* __restrict__ Wthi, const ushort* __restrict__ Wtlo,
               const float* __restrict__ bias,
               float* __restrict__ Y1, float* __restrict__ Y2, int ldy1, int ldy2,
               float* __restrict__ als, float* __restrict__ ald,
               const float* __restrict__ a_src, const float* __restrict__ a_dst,
               int n)
{
    constexpr int NH  = NTOT / 2;     // cols per wave
    constexpr int NF  = NH / 16;      // 16-wide col frags per wave
    constexpr int NKT = KTOT / 32;    // K tiles

    // pad to 40 u16 (80 B = 5*16B): 16B-aligned b128 reads, uniform bank spread
    __shared__ ushort Ahi[128][40], Alo[128][40];
    __shared__ ushort Bhi[NTOT][40], Blo[NTOT][40];

    const int t  = threadIdx.x;
    const int l  = t & 63, w = t >> 6;
    const int wm = w >> 1, wc = w & 1;          // 2x2 wave grid
    const int lc = l & 15, lq = l >> 4;
    const int bm = blockIdx.x * 128;
    const int colbase = wc * NH;

    f32x4 acc[4][NF];
#pragma unroll
    for (int mf = 0; mf < 4; ++mf)
#pragma unroll
        for (int nf = 0; nf < NF; ++nf)
            acc[mf][nf] = (f32x4){0.f, 0.f, 0.f, 0.f};

    const int kq = (t & 7) * 4;       // k offset for A staging (float4)
    const int rb = t >> 3;            // row 0..31 per pass

    for (int kt = 0; kt < NKT; ++kt) {
        const int k0 = kt * 32;
        // ---- select X source (virtual K-concat) ----
        const float* xp; int ldx, koff;
        if (k0 < K1)      { xp = X1; ldx = ldx1; koff = k0; }
        else if (k0 < K2) { xp = X2; ldx = ldx2; koff = k0 - K1; }
        else              { xp = X3; ldx = ldx3; koff = k0 - K2; }

        // ---- stage A: 128 rows x 32 k, f32 -> bf16 hi/lo ----
#pragma unroll
        for (int p = 0; p < 4; ++p) {
            int rr = rb + p * 32;
            int gr = bm + rr;
            float4 v = make_float4(0.f, 0.f, 0.f, 0.f);
            if (gr < n) v = *(const float4*)&xp[(size_t)gr * ldx + koff + kq];
            ushort4v hh, ll;
            const float* vp = &v.x;
#pragma unroll
            for (int e = 0; e < 4; ++e) {
                ushort h = f2bf(vp[e]);
                hh[e] = h;
                ll[e] = f2bf(vp[e] - bf2f(h));
            }
            *(ushort4v*)&Ahi[rr][kq] = hh;
            *(ushort4v*)&Alo[rr][kq] = ll;
        }

        // ---- stage B: pre-tiled bf16 copy [NTOT][32] -> LDS ----
        {
            const ushort* wb0 = &Wthi[(size_t)kt * NTOT * 32];
            const ushort* wb1 = &Wtlo[(size_t)kt * NTOT * 32];
#pragma unroll
            for (int ii = 0; ii < (NTOT * 4) / 256; ++ii) {
                int i = t + ii * 256;
                int nn = i >> 2, q = (i & 3) * 8;
                *(ushort8v*)&Bhi[nn][q] = *(const ushort8v*)&wb0[nn * 32 + q];
                *(ushort8v*)&Blo[nn][q] = *(const ushort8v*)&wb1[nn * 32 + q];
            }
        }
        __syncthreads();

        // ---- MFMA inner: 3 passes (hi*hi + hi*lo + lo*hi) ----
        short8 ah[4], alv[4];
#pragma unroll
        for (int mf = 0; mf < 4; ++mf) {
            ah[mf]  = *(const short8*)&Ahi[wm * 64 + mf * 16 + lc][lq * 8];
            alv[mf] = *(const short8*)&Alo[wm * 64 + mf * 16 + lc][lq * 8];
        }
#pragma unroll
        for (int nf = 0; nf < NF; ++nf) {
            short8 bh = *(const short8*)&Bhi[colbase + nf * 16 + lc][lq * 8];
            short8 bl = *(const short8*)&Blo[colbase + nf * 16 + lc][lq * 8];
#pragma unroll
            for (int mf = 0; mf < 4; ++mf) {
                acc[mf][nf] = __builtin_amdgcn_mfma_f32_16x16x32_bf16(ah[mf],  bh, acc[mf][nf], 0, 0, 0);
                acc[mf][nf] = __builtin_amdgcn_mfma_f32_16x16x32_bf16(ah[mf],  bl, acc[mf][nf], 0, 0, 0);
                acc[mf][nf] = __builtin_amdgcn_mfma_f32_16x16x32_bf16(alv[mf], bh, acc[mf][nf], 0, 0, 0);
            }
        }
        __syncthreads();
    }

    // ---- attention-logit epilogue (MFMA layout: col = lc, rows = lq*4+r) ----
    if constexpr (AHH > 0) {
        constexpr int FPH = ACC / 16;     // frags per head
        constexpr int NG  = NF / FPH;     // head groups per wave
#pragma unroll
        for (int g = 0; g < NG; ++g) {
            if (colbase + g * ACC < ATTN) {
#pragma unroll
                for (int mf = 0; mf < 4; ++mf) {
                    float ps[4] = {0.f, 0.f, 0.f, 0.f};
                    float pd[4] = {0.f, 0.f, 0.f, 0.f};
#pragma unroll
                    for (int j = 0; j < FPH; ++j) {
                        int col = colbase + g * ACC + j * 16 + lc;
                        float av = a_src[col], dv = a_dst[col];
#pragma unroll
                        for (int r = 0; r < 4; ++r) {
                            ps[r] = fmaf(acc[mf][g * FPH + j][r], av, ps[r]);
                            pd[r] = fmaf(acc[mf][g * FPH + j][r], dv, pd[r]);
                        }
                    }
#pragma unroll
                    for (int off = 1; off < 16; off <<= 1)
#pragma unroll
                        for (int r = 0; r < 4; ++r) {
                            ps[r] += __shfl_xor(ps[r], off);
                            pd[r] += __shfl_xor(pd[r], off);
                        }
                    if (lc == 0) {
                        int h = (colbase + g * ACC) / ACC;
#pragma unroll
                        for (int r = 0; r < 4; ++r) {
                            int row = bm + wm * 64 + mf * 16 + lq * 4 + r;
                            if (row < n) {
                                als[(size_t)row * AHH + h] = ps[r];
                                ald[(size_t)row * AHH + h] = pd[r];
                            }
                        }
                    }
                }
            }
        }
    }

    // ---- store (+ bias for cols >= BIAS_OFF) ----
#pragma unroll
    for (int mf = 0; mf < 4; ++mf) {
        int rowb = bm + wm * 64 + mf * 16 + lq * 4;
#pragma unroll
        for (int nf = 0; nf < NF; ++nf) {
            int col = colbase + nf * 16 + lc;
            float bv = 0.f;
            if constexpr (BIAS_OFF < NTOT) {
                if (col >= BIAS_OFF) bv = bias[col - BIAS_OFF];
            }
#pragma unroll
            for (int r = 0; r < 4; ++r) {
                int row = rowb + r;
                if (row < n) {
                    float v = acc[mf][nf][r] + bv;
                    if (col < CSPLIT)
                        Y1[(size_t)row * ldy1 + col] = v;
                    else
                        Y2[(size_t)row * ldy2 + (col - CSPLIT)] = v;
                }
            }
        }
    }
}

// ---------------------------------------------------------------------------
// CSR build: histogram -> block sums -> scan sums -> per-block scan -> fill
// ---------------------------------------------------------------------------
__global__ void deg_kernel(const int* __restrict__ ei, int* __restrict__ deg)
{
    int t = blockIdx.x * blockDim.x + threadIdx.x;
    if (t < NE) atomicAdd(&deg[ei[NE + t]], 1);   // dst of edge t
}

__global__ void block_sum_kernel(const int* __restrict__ deg, int* __restrict__ bsum)
{
    int node = blockIdx.x * 256 + threadIdx.x;
    int v = (node < NN) ? deg[node] + 1 : 0;      // +1 = self loop
#pragma unroll
    for (int off = 32; off > 0; off >>= 1) v += __shfl_down(v, off);
    __shared__ int sh[4];
    if ((threadIdx.x & 63) == 0) sh[threadIdx.x >> 6] = v;
    __syncthreads();
    if (threadIdx.x == 0) bsum[blockIdx.x] = sh[0] + sh[1] + sh[2] + sh[3];
}

__global__ void scan_sums_kernel(const int* __restrict__ bsum, int* __restrict__ bsumx,
                                 int* __restrict__ rowptr)
{
    if (threadIdx.x == 0) {
        int run = 0;
        for (int i = 0; i < NB; ++i) { bsumx[i] = run; run += bsum[i]; }
        rowptr[NN] = run;    // == EP
    }
}

__global__ void scan_blocks_kernel(const int* __restrict__ deg, const int* __restrict__ bsumx,
                                   int* __restrict__ rowptr, int* __restrict__ cursor)
{
    __shared__ int sh[256];
    int node = blockIdx.x * 256 + threadIdx.x;
    int v = (node < NN) ? deg[node] + 1 : 0;
    sh[threadIdx.x] = v;
    __syncthreads();
#pragma unroll
    for (int off = 1; off < 256; off <<= 1) {
        int tv = (threadIdx.x >= off) ? sh[threadIdx.x - off] : 0;
        __syncthreads();
        sh[threadIdx.x] += tv;
        __syncthreads();
    }
    if (node < NN) {
        int excl = bsumx[blockIdx.x] + sh[threadIdx.x] - v;
        rowptr[node] = excl;
        cursor[node] = excl;
    }
}

__global__ void fill_kernel(const int* __restrict__ ei, int* __restrict__ cursor,
                            int* __restrict__ csr_src)
{
    int t = blockIdx.x * blockDim.x + threadIdx.x;
    if (t >= EP) return;
    int s, d;
    if (t < NE) { s = ei[t]; d = ei[NE + t]; }
    else        { s = d = t - NE; }
    int pos = atomicAdd(&cursor[d], 1);
    csr_src[pos] = s;
}

// ---------------------------------------------------------------------------
// Per-node aggregation with online softmax + fused epilogue.
// ---------------------------------------------------------------------------
template<int HH, int CC, bool DOELU>
__global__ __launch_bounds__(256)
void node_agg_kernel(const int* __restrict__ rowptr, const int* __restrict__ csr_src,
                     const float* __restrict__ xh, const float* __restrict__ als,
                     const float* __restrict__ ald, const float* __restrict__ b,
                     const float* __restrict__ res, float* __restrict__ out, int n)
{
    constexpr int HCL = HH * CC;
    constexpr int NPB = 256 / HCL;
    const int ln = threadIdx.x / HCL;
    const int lc = threadIdx.x - ln * HCL;
    const int node = blockIdx.x * NPB + ln;
    if (node >= n) return;
    const int h = lc / CC;
    const int e0 = rowptr[node], e1 = rowptr[node + 1];
    const float aldv = ald[(size_t)node * HH + h];

    float m = -1e30f, denom = 0.f, acc = 0.f;
    for (int e = e0; e < e1; ++e) {
        int s = csr_src[e];
        float sc = leaky(als[(size_t)s * HH + h] + aldv);
        float nm = fmaxf(m, sc);
        float scale = __expf(m - nm);
        float w = __expf(sc - nm);
        denom = denom * scale + w;
        acc = acc * scale + xh[(size_t)s * HCL + lc] * w;
        m = nm;
    }
    float v = acc / denom + b[lc] + res[(size_t)node * HCL + lc];
    if (DOELU) v = v > 0.f ? v : (__expf(v) - 1.f);
    out[(size_t)node * HCL + lc] = v;
}

// ---------------------------------------------------------------------------
extern "C" void kernel_launch(void* const* d_in, const int* in_sizes, int n_in,
                              void* d_out, int out_size, void* d_ws, size_t ws_size,
                              hipStream_t stream)
{
    const float* x    = (const float*)d_in[0];
    const int*   ei   = (const int*)d_in[1];
    const float* W0   = (const float*)d_in[2];
    const float* b0   = (const float*)d_in[3];
    const float* as0  = (const float*)d_in[4];
    const float* ad0  = (const float*)d_in[5];
    const float* W1   = (const float*)d_in[6];
    const float* b1   = (const float*)d_in[7];
    const float* as1  = (const float*)d_in[8];
    const float* ad1  = (const float*)d_in[9];
    const float* W2   = (const float*)d_in[10];
    const float* b2   = (const float*)d_in[11];
    const float* as2  = (const float*)d_in[12];
    const float* ad2  = (const float*)d_in[13];
    const float* sk0W = (const float*)d_in[14];
    const float* sk0b = (const float*)d_in[15];
    const float* sk2W = (const float*)d_in[16];
    const float* sk2b = (const float*)d_in[17];
    const float* jkW  = (const float*)d_in[18];
    const float* jkb  = (const float*)d_in[19];
    float* out = (float*)d_out;

    float* ws = (float*)d_ws;
    size_t off = 0;
    float* s_x0  = ws + off; off += (size_t)NN * 128;
    float* s_x1  = ws + off; off += (size_t)NN * 128;
    float* s_h2  = ws + off; off += (size_t)NN * 64;
    float* s_xh  = ws + off; off += (size_t)NN * 128;
    float* s_als = ws + off; off += (size_t)NN * 4;
    float* s_ald = ws + off; off += (size_t)NN * 4;
    int* i_deg    = (int*)(ws + off); off += NN;
    int* i_rowptr = (int*)(ws + off); off += NN + 1;
    int* i_cursor = (int*)(ws + off); off += NN;
    int* i_csrsrc = (int*)(ws + off); off += EP;
    int* i_bsum   = (int*)(ws + off); off += NB;
    int* i_bsumx  = (int*)(ws + off); off += NB;
    off = (off + 3) & ~(size_t)3;     // 16B-align the bf16 weight tiles
    // pre-tiled split-bf16 weights: [K/32][NT][32] u16 each (hi, lo)
    ushort* wt0h = (ushort*)(ws + off); off += 32768;   // 8*256*32 u16
    ushort* wt0l = (ushort*)(ws + off); off += 32768;
    ushort* wt1h = (ushort*)(ws + off); off += 8192;    // 4*128*32 u16
    ushort* wt1l = (ushort*)(ws + off); off += 8192;
    ushort* wt2h = (ushort*)(ws + off); off += 8192;    // 4*128*32 u16
    ushort* wt2l = (ushort*)(ws + off); off += 8192;
    ushort* wtjh = (ushort*)(ws + off); off += 10240;   // 10*64*32 u16
    ushort* wtjl = (ushort*)(ws + off); off += 10240;

    const int GM = (NN + 127) / 128;    // 782 row blocks
    const int BIG = 1 << 30;

    // ======================= CSR build (shared by all 3 layers) ==========
    hipMemsetAsync(i_deg, 0, (size_t)NN * sizeof(int), stream);
    deg_kernel<<<(NE + 255) / 256, 256, 0, stream>>>(ei, i_deg);
    block_sum_kernel<<<NB, 256, 0, stream>>>(i_deg, i_bsum);
    scan_sums_kernel<<<1, 64, 0, stream>>>(i_bsum, i_bsumx, i_rowptr);
    scan_blocks_kernel<<<NB, 256, 0, stream>>>(i_deg, i_bsumx, i_rowptr, i_cursor);
    fill_kernel<<<(EP + 255) / 256, 256, 0, stream>>>(ei, i_cursor, i_csrsrc);

    // ======================= weight pre-tiling (split bf16) ==============
    pretile_kernel<<<256, 256, 0, stream>>>(W0, sk0W, 256, 128, 256, wt0h, wt0l);
    pretile_kernel<<<64,  256, 0, stream>>>(W1, nullptr, 128, 128, 128, wt1h, wt1l);
    pretile_kernel<<<64,  256, 0, stream>>>(W2, sk2W, 128, 64, 128, wt2h, wt2l);
    pretile_kernel<<<80,  256, 0, stream>>>(jkW, nullptr, 320, 64, 64, wtjh, wtjl);

    // ======= layer 0: fused [xh0 | res0] = x @ [W0 | sk0W] (K=256, N=256)
    gemm_mfma<256, 256, 256, 256, 128, 128, 4, 32, 128>
        <<<GM, 256, 0, stream>>>(
        x, nullptr, nullptr, 256, 0, 0, wt0h, wt0l, sk0b,
        s_xh, s_x0, 128, 128, s_als, s_ald, as0, ad0, NN);
    node_agg_kernel<4, 32, true><<<(NN + 1) / 2, 256, 0, stream>>>(
        i_rowptr, i_csrsrc, s_xh, s_als, s_ald, b0, s_x0, s_x0, NN);

    // ======= layer 1: xh1 = x0 @ W1 (K=128, N=128, no bias in GEMM)
    gemm_mfma<128, 128, 128, 128, 128, (1 << 30), 4, 32, 128>
        <<<GM, 256, 0, stream>>>(
        s_x0, nullptr, nullptr, 128, 0, 0, wt1h, wt1l, nullptr,
        s_xh, nullptr, 128, 0, s_als, s_ald, as1, ad1, NN);
    node_agg_kernel<4, 32, true><<<(NN + 1) / 2, 256, 0, stream>>>(
        i_rowptr, i_csrsrc, s_xh, s_als, s_ald, b1, s_x0, s_x1, NN);

    // ======= layer 2: fused [xh2 | res2] = x1 @ [W2 | sk2W] (K=128, N=128)
    gemm_mfma<128, 128, 128, 128, 64, 64, 1, 64, 64>
        <<<GM, 256, 0, stream>>>(
        s_x1, nullptr, nullptr, 128, 0, 0, wt2h, wt2l, sk2b,
        s_xh, s_h2, 64, 64, s_als, s_ald, as2, ad2, NN);
    node_agg_kernel<1, 64, false><<<(NN + 3) / 4, 256, 0, stream>>>(
        i_rowptr, i_csrsrc, s_xh, s_als, s_ald, b2, s_h2, s_h2, NN);

    // ======= JumpingKnowledge: out = [x0|x1|h2] @ jkW + jkb (K=320, N=64)
    gemm_mfma<320, 64, 128, 256, 64, 0, 0, 16, 0>
        <<<GM, 256, 0, stream>>>(
        s_x0, s_x1, s_h2, 128, 128, 64, wtjh, wtjl, jkb,
        out, nullptr, 64, 0, nullptr, nullptr, nullptr, nullptr, NN);
}

// Round 2
// 835.811 us; speedup vs baseline: 1.2041x; 1.2041x over previous
//
#include <hip/hip_runtime.h>
#include <hip/hip_bf16.h>
#include <cstdint>

static constexpr int NN = 100000;     // nodes
static constexpr int NE = 800000;     // edges (without self loops)
static constexpr int EP = NE + NN;    // edges incl. self loops
static constexpr int NB = (NN + 255) / 256;  // scan blocks

typedef unsigned short ushort;
typedef __attribute__((ext_vector_type(8))) short short8;
typedef __attribute__((ext_vector_type(8))) ushort ushort8v;
typedef __attribute__((ext_vector_type(4))) ushort ushort4v;
typedef __attribute__((ext_vector_type(4))) float f32x4;

__device__ __forceinline__ float leaky(float x) { return x > 0.f ? x : 0.2f * x; }

// float -> bf16 bits (RNE)
__device__ __forceinline__ ushort f2bf(float f) {
    unsigned int u = __float_as_uint(f);
    u += 0x7fffu + ((u >> 16) & 1u);
    return (ushort)(u >> 16);
}
__device__ __forceinline__ float bf2f(ushort h) {
    return __uint_as_float(((unsigned int)h) << 16);
}

// ---------------------------------------------------------------------------
// Weight pre-tiling: W (virtual concat [Wa | Wb], K x NT, row-major) ->
//   Whi/Wlo: [K/32][NT][32] bf16 (hi + lo split).  Tiny, runs once per layer.
// ---------------------------------------------------------------------------
__global__ void pretile_kernel(const float* __restrict__ Wa, const float* __restrict__ Wb,
                               int K, int CS, int NT,
                               ushort* __restrict__ Whi, ushort* __restrict__ Wlo)
{
    int idx = blockIdx.x * 256 + threadIdx.x;
    if (idx >= K * NT) return;
    int k = idx / NT, c = idx - k * NT;
    float v = (c < CS) ? Wa[(size_t)k * CS + c] : Wb[(size_t)k * (NT - CS) + (c - CS)];
    ushort h = f2bf(v);
    ushort l = f2bf(v - bf2f(h));
    size_t o = ((size_t)(k >> 5) * NT + c) * 32 + (k & 31);
    Whi[o] = h; Wlo[o] = l;
}

// ---------------------------------------------------------------------------
// Split-bf16 MFMA GEMM (3-pass hi/lo emulation, ~fp32 accuracy).
//   Y = X @ W, X = virtual concat of up to 3 sources split at K1,K2.
//   W pre-tiled as Wthi/Wtlo [K/32][NTOT][32] bf16.
//   Block: 256 thr (4 waves, 2x2), tile 128 rows x NCB cols; grid.y covers
//   NTOT/NCB col-blocks. Per-wave tile 64x64 -> acc = 64 VGPR (no spill).
//   bias[c-BIAS_OFF] added to cols >= BIAS_OFF; Y split at CSPLIT into Y1/Y2.
//   Attention-logit epilogue for cols < ATTN (heads of width ACC), which must
//   live entirely in col-block 0.
// MFMA 16x16x32 bf16 layouts (m89/m91-verified):
//   A: lane l holds A[l&15][8*(l>>4)+e]; B: lane l holds B[8*(l>>4)+e][l&15]
//   D: lane l reg r = D[(l>>4)*4+r][l&15]
// ---------------------------------------------------------------------------
template<int KTOT, int NTOT, int NCB, int K1, int K2, int CSPLIT, int BIAS_OFF,
         int AHH, int ACC, int ATTN>
__global__ __launch_bounds__(256, 3)
void gemm_mfma(const float* __restrict__ X1, const float* __restrict__ X2,
               const float* __restrict__ X3, int ldx1, int ldx2, int ldx3,
               const ushort* __restrict__ Wthi, const ushort* __restrict__ Wtlo,
               const float* __restrict__ bias,
               float* __restrict__ Y1, float* __restrict__ Y2, int ldy1, int ldy2,
               float* __restrict__ als, float* __restrict__ ald,
               const float* __restrict__ a_src, const float* __restrict__ a_dst,
               int n)
{
    constexpr int NH  = NCB / 2;      // cols per wave
    constexpr int NF  = NH / 16;      // 16-wide col frags per wave
    constexpr int NKT = KTOT / 32;    // K tiles

    // pad to 40 u16 (80 B): 16B-aligned b128 reads, 2-way-max bank aliasing
    __shared__ ushort Ahi[128][40], Alo[128][40];
    __shared__ ushort Bhi[NCB][40], Blo[NCB][40];

    const int t  = threadIdx.x;
    const int l  = t & 63, w = t >> 6;
    const int wm = w >> 1, wc = w & 1;          // 2x2 wave grid
    const int lc = l & 15, lq = l >> 4;
    const int bm = blockIdx.x * 128;
    const int cbase = blockIdx.y * NCB;         // global col base of block
    const int colb = wc * NH;                   // wave col base within block

    f32x4 acc[4][NF];
#pragma unroll
    for (int mf = 0; mf < 4; ++mf)
#pragma unroll
        for (int nf = 0; nf < NF; ++nf)
            acc[mf][nf] = (f32x4){0.f, 0.f, 0.f, 0.f};

    const int kq = (t & 7) * 4;       // k offset for A staging (float4)
    const int rb = t >> 3;            // row 0..31 per pass

    for (int kt = 0; kt < NKT; ++kt) {
        const int k0 = kt * 32;
        // ---- select X source (virtual K-concat) ----
        const float* xp; int ldx, koff;
        if (k0 < K1)      { xp = X1; ldx = ldx1; koff = k0; }
        else if (k0 < K2) { xp = X2; ldx = ldx2; koff = k0 - K1; }
        else              { xp = X3; ldx = ldx3; koff = k0 - K2; }

        // ---- stage A: 128 rows x 32 k, f32 -> bf16 hi/lo ----
#pragma unroll
        for (int p = 0; p < 4; ++p) {
            int rr = rb + p * 32;
            int gr = bm + rr;
            float4 v = make_float4(0.f, 0.f, 0.f, 0.f);
            if (gr < n) v = *(const float4*)&xp[(size_t)gr * ldx + koff + kq];
            ushort4v hh, ll;
            const float* vp = &v.x;
#pragma unroll
            for (int e = 0; e < 4; ++e) {
                ushort h = f2bf(vp[e]);
                hh[e] = h;
                ll[e] = f2bf(vp[e] - bf2f(h));
            }
            *(ushort4v*)&Ahi[rr][kq] = hh;
            *(ushort4v*)&Alo[rr][kq] = ll;
        }

        // ---- stage B: pre-tiled bf16 copy [NCB][32] -> LDS ----
        {
            const ushort* wb0 = &Wthi[((size_t)kt * NTOT + cbase) * 32];
            const ushort* wb1 = &Wtlo[((size_t)kt * NTOT + cbase) * 32];
#pragma unroll
            for (int ii = 0; ii < NCB / 64; ++ii) {
                int i = t + ii * 256;
                int nn = i >> 2, q = (i & 3) * 8;
                *(ushort8v*)&Bhi[nn][q] = *(const ushort8v*)&wb0[nn * 32 + q];
                *(ushort8v*)&Blo[nn][q] = *(const ushort8v*)&wb1[nn * 32 + q];
            }
        }
        __syncthreads();

        // ---- MFMA inner: 3 passes (hi*hi + hi*lo + lo*hi) ----
        short8 ah[4], alv[4];
#pragma unroll
        for (int mf = 0; mf < 4; ++mf) {
            ah[mf]  = *(const short8*)&Ahi[wm * 64 + mf * 16 + lc][lq * 8];
            alv[mf] = *(const short8*)&Alo[wm * 64 + mf * 16 + lc][lq * 8];
        }
#pragma unroll
        for (int nf = 0; nf < NF; ++nf) {
            short8 bh = *(const short8*)&Bhi[colb + nf * 16 + lc][lq * 8];
            short8 bl = *(const short8*)&Blo[colb + nf * 16 + lc][lq * 8];
#pragma unroll
            for (int mf = 0; mf < 4; ++mf) {
                acc[mf][nf] = __builtin_amdgcn_mfma_f32_16x16x32_bf16(ah[mf],  bh, acc[mf][nf], 0, 0, 0);
                acc[mf][nf] = __builtin_amdgcn_mfma_f32_16x16x32_bf16(ah[mf],  bl, acc[mf][nf], 0, 0, 0);
                acc[mf][nf] = __builtin_amdgcn_mfma_f32_16x16x32_bf16(alv[mf], bh, acc[mf][nf], 0, 0, 0);
            }
        }
        __syncthreads();
    }

    // ---- attention-logit epilogue (MFMA layout: col = lc, rows = lq*4+r) ----
    if constexpr (AHH > 0) {
        if (cbase == 0) {
            constexpr int FPH = ACC / 16;     // frags per head
            constexpr int NG  = NF / FPH;     // head groups per wave
#pragma unroll
            for (int g = 0; g < NG; ++g) {
                if (colb + g * ACC < ATTN) {
#pragma unroll
                    for (int mf = 0; mf < 4; ++mf) {
                        float ps[4] = {0.f, 0.f, 0.f, 0.f};
                        float pd[4] = {0.f, 0.f, 0.f, 0.f};
#pragma unroll
                        for (int j = 0; j < FPH; ++j) {
                            int col = colb + g * ACC + j * 16 + lc;
                            float av = a_src[col], dv = a_dst[col];
#pragma unroll
                            for (int r = 0; r < 4; ++r) {
                                ps[r] = fmaf(acc[mf][g * FPH + j][r], av, ps[r]);
                                pd[r] = fmaf(acc[mf][g * FPH + j][r], dv, pd[r]);
                            }
                        }
#pragma unroll
                        for (int off = 1; off < 16; off <<= 1)
#pragma unroll
                            for (int r = 0; r < 4; ++r) {
                                ps[r] += __shfl_xor(ps[r], off);
                                pd[r] += __shfl_xor(pd[r], off);
                            }
                        if (lc == 0) {
                            int h = (colb + g * ACC) / ACC;
#pragma unroll
                            for (int r = 0; r < 4; ++r) {
                                int row = bm + wm * 64 + mf * 16 + lq * 4 + r;
                                if (row < n) {
                                    als[(size_t)row * AHH + h] = ps[r];
                                    ald[(size_t)row * AHH + h] = pd[r];
                                }
                            }
                        }
                    }
                }
            }
        }
    }

    // ---- store (+ bias for cols >= BIAS_OFF) ----
#pragma unroll
    for (int mf = 0; mf < 4; ++mf) {
        int rowb = bm + wm * 64 + mf * 16 + lq * 4;
#pragma unroll
        for (int nf = 0; nf < NF; ++nf) {
            int col = cbase + colb + nf * 16 + lc;
            float bv = 0.f;
            if constexpr (BIAS_OFF < NTOT) {
                if (col >= BIAS_OFF) bv = bias[col - BIAS_OFF];
            }
#pragma unroll
            for (int r = 0; r < 4; ++r) {
                int row = rowb + r;
                if (row < n) {
                    float v = acc[mf][nf][r] + bv;
                    if (col < CSPLIT)
                        Y1[(size_t)row * ldy1 + col] = v;
                    else
                        Y2[(size_t)row * ldy2 + (col - CSPLIT)] = v;
                }
            }
        }
    }
}

// ---------------------------------------------------------------------------
// CSR build: histogram -> block sums -> scan sums -> per-block scan -> fill
// ---------------------------------------------------------------------------
__global__ void deg_kernel(const int* __restrict__ ei, int* __restrict__ deg)
{
    int t = blockIdx.x * blockDim.x + threadIdx.x;
    if (t < NE) atomicAdd(&deg[ei[NE + t]], 1);   // dst of edge t
}

__global__ void block_sum_kernel(const int* __restrict__ deg, int* __restrict__ bsum)
{
    int node = blockIdx.x * 256 + threadIdx.x;
    int v = (node < NN) ? deg[node] + 1 : 0;      // +1 = self loop
#pragma unroll
    for (int off = 32; off > 0; off >>= 1) v += __shfl_down(v, off);
    __shared__ int sh[4];
    if ((threadIdx.x & 63) == 0) sh[threadIdx.x >> 6] = v;
    __syncthreads();
    if (threadIdx.x == 0) bsum[blockIdx.x] = sh[0] + sh[1] + sh[2] + sh[3];
}

__global__ void scan_sums_kernel(const int* __restrict__ bsum, int* __restrict__ bsumx,
                                 int* __restrict__ rowptr)
{
    if (threadIdx.x == 0) {
        int run = 0;
        for (int i = 0; i < NB; ++i) { bsumx[i] = run; run += bsum[i]; }
        rowptr[NN] = run;    // == EP
    }
}

__global__ void scan_blocks_kernel(const int* __restrict__ deg, const int* __restrict__ bsumx,
                                   int* __restrict__ rowptr, int* __restrict__ cursor)
{
    __shared__ int sh[256];
    int node = blockIdx.x * 256 + threadIdx.x;
    int v = (node < NN) ? deg[node] + 1 : 0;
    sh[threadIdx.x] = v;
    __syncthreads();
#pragma unroll
    for (int off = 1; off < 256; off <<= 1) {
        int tv = (threadIdx.x >= off) ? sh[threadIdx.x - off] : 0;
        __syncthreads();
        sh[threadIdx.x] += tv;
        __syncthreads();
    }
    if (node < NN) {
        int excl = bsumx[blockIdx.x] + sh[threadIdx.x] - v;
        rowptr[node] = excl;
        cursor[node] = excl;
    }
}

__global__ void fill_kernel(const int* __restrict__ ei, int* __restrict__ cursor,
                            int* __restrict__ csr_src)
{
    int t = blockIdx.x * blockDim.x + threadIdx.x;
    if (t >= EP) return;
    int s, d;
    if (t < NE) { s = ei[t]; d = ei[NE + t]; }
    else        { s = d = t - NE; }
    int pos = atomicAdd(&cursor[d], 1);
    csr_src[pos] = s;
}

// ---------------------------------------------------------------------------
// Per-node aggregation with online softmax + fused epilogue.
// ---------------------------------------------------------------------------
template<int HH, int CC, bool DOELU>
__global__ __launch_bounds__(256)
void node_agg_kernel(const int* __restrict__ rowptr, const int* __restrict__ csr_src,
                     const float* __restrict__ xh, const float* __restrict__ als,
                     const float* __restrict__ ald, const float* __restrict__ b,
                     const float* __restrict__ res, float* __restrict__ out, int n)
{
    constexpr int HCL = HH * CC;
    constexpr int NPB = 256 / HCL;
    const int ln = threadIdx.x / HCL;
    const int lc = threadIdx.x - ln * HCL;
    const int node = blockIdx.x * NPB + ln;
    if (node >= n) return;
    const int h = lc / CC;
    const int e0 = rowptr[node], e1 = rowptr[node + 1];
    const float aldv = ald[(size_t)node * HH + h];

    float m = -1e30f, denom = 0.f, acc = 0.f;
    for (int e = e0; e < e1; ++e) {
        int s = csr_src[e];
        float sc = leaky(als[(size_t)s * HH + h] + aldv);
        float nm = fmaxf(m, sc);
        float scale = __expf(m - nm);
        float w = __expf(sc - nm);
        denom = denom * scale + w;
        acc = acc * scale + xh[(size_t)s * HCL + lc] * w;
        m = nm;
    }
    float v = acc / denom + b[lc] + res[(size_t)node * HCL + lc];
    if (DOELU) v = v > 0.f ? v : (__expf(v) - 1.f);
    out[(size_t)node * HCL + lc] = v;
}

// ---------------------------------------------------------------------------
extern "C" void kernel_launch(void* const* d_in, const int* in_sizes, int n_in,
                              void* d_out, int out_size, void* d_ws, size_t ws_size,
                              hipStream_t stream)
{
    const float* x    = (const float*)d_in[0];
    const int*   ei   = (const int*)d_in[1];
    const float* W0   = (const float*)d_in[2];
    const float* b0   = (const float*)d_in[3];
    const float* as0  = (const float*)d_in[4];
    const float* ad0  = (const float*)d_in[5];
    const float* W1   = (const float*)d_in[6];
    const float* b1   = (const float*)d_in[7];
    const float* as1  = (const float*)d_in[8];
    const float* ad1  = (const float*)d_in[9];
    const float* W2   = (const float*)d_in[10];
    const float* b2   = (const float*)d_in[11];
    const float* as2  = (const float*)d_in[12];
    const float* ad2  = (const float*)d_in[13];
    const float* sk0W = (const float*)d_in[14];
    const float* sk0b = (const float*)d_in[15];
    const float* sk2W = (const float*)d_in[16];
    const float* sk2b = (const float*)d_in[17];
    const float* jkW  = (const float*)d_in[18];
    const float* jkb  = (const float*)d_in[19];
    float* out = (float*)d_out;

    float* ws = (float*)d_ws;
    size_t off = 0;
    float* s_x0  = ws + off; off += (size_t)NN * 128;
    float* s_x1  = ws + off; off += (size_t)NN * 128;
    float* s_h2  = ws + off; off += (size_t)NN * 64;
    float* s_xh  = ws + off; off += (size_t)NN * 128;
    float* s_als = ws + off; off += (size_t)NN * 4;
    float* s_ald = ws + off; off += (size_t)NN * 4;
    int* i_deg    = (int*)(ws + off); off += NN;
    int* i_rowptr = (int*)(ws + off); off += NN + 1;
    int* i_cursor = (int*)(ws + off); off += NN;
    int* i_csrsrc = (int*)(ws + off); off += EP;
    int* i_bsum   = (int*)(ws + off); off += NB;
    int* i_bsumx  = (int*)(ws + off); off += NB;
    off = (off + 3) & ~(size_t)3;     // 16B-align the bf16 weight tiles
    // pre-tiled split-bf16 weights: [K/32][NT][32] u16 each (hi, lo)
    ushort* wt0h = (ushort*)(ws + off); off += 32768;   // 8*256*32 u16
    ushort* wt0l = (ushort*)(ws + off); off += 32768;
    ushort* wt1h = (ushort*)(ws + off); off += 8192;    // 4*128*32 u16
    ushort* wt1l = (ushort*)(ws + off); off += 8192;
    ushort* wt2h = (ushort*)(ws + off); off += 8192;    // 4*128*32 u16
    ushort* wt2l = (ushort*)(ws + off); off += 8192;
    ushort* wtjh = (ushort*)(ws + off); off += 10240;   // 10*64*32 u16
    ushort* wtjl = (ushort*)(ws + off); off += 10240;

    const int GM = (NN + 127) / 128;    // 782 row blocks
    constexpr int BIG = 1 << 30;

    // ======================= CSR build (shared by all 3 layers) ==========
    hipMemsetAsync(i_deg, 0, (size_t)NN * sizeof(int), stream);
    deg_kernel<<<(NE + 255) / 256, 256, 0, stream>>>(ei, i_deg);
    block_sum_kernel<<<NB, 256, 0, stream>>>(i_deg, i_bsum);
    scan_sums_kernel<<<1, 64, 0, stream>>>(i_bsum, i_bsumx, i_rowptr);
    scan_blocks_kernel<<<NB, 256, 0, stream>>>(i_deg, i_bsumx, i_rowptr, i_cursor);
    fill_kernel<<<(EP + 255) / 256, 256, 0, stream>>>(ei, i_cursor, i_csrsrc);

    // ======================= weight pre-tiling (split bf16) ==============
    pretile_kernel<<<256, 256, 0, stream>>>(W0, sk0W, 256, 128, 256, wt0h, wt0l);
    pretile_kernel<<<64,  256, 0, stream>>>(W1, nullptr, 128, 128, 128, wt1h, wt1l);
    pretile_kernel<<<64,  256, 0, stream>>>(W2, sk2W, 128, 64, 128, wt2h, wt2l);
    pretile_kernel<<<80,  256, 0, stream>>>(jkW, nullptr, 320, 64, 64, wtjh, wtjl);

    // ======= layer 0: fused [xh0 | res0] = x @ [W0 | sk0W] (K=256, N=256)
    gemm_mfma<256, 256, 128, 256, 256, 128, 128, 4, 32, 128>
        <<<dim3(GM, 2), 256, 0, stream>>>(
        x, nullptr, nullptr, 256, 0, 0, wt0h, wt0l, sk0b,
        s_xh, s_x0, 128, 128, s_als, s_ald, as0, ad0, NN);
    node_agg_kernel<4, 32, true><<<(NN + 1) / 2, 256, 0, stream>>>(
        i_rowptr, i_csrsrc, s_xh, s_als, s_ald, b0, s_x0, s_x0, NN);

    // ======= layer 1: xh1 = x0 @ W1 (K=128, N=128, no bias in GEMM)
    gemm_mfma<128, 128, 128, 128, 128, 128, BIG, 4, 32, 128>
        <<<dim3(GM, 1), 256, 0, stream>>>(
        s_x0, nullptr, nullptr, 128, 0, 0, wt1h, wt1l, nullptr,
        s_xh, nullptr, 128, 0, s_als, s_ald, as1, ad1, NN);
    node_agg_kernel<4, 32, true><<<(NN + 1) / 2, 256, 0, stream>>>(
        i_rowptr, i_csrsrc, s_xh, s_als, s_ald, b1, s_x0, s_x1, NN);

    // ======= layer 2: fused [xh2 | res2] = x1 @ [W2 | sk2W] (K=128, N=128)
    gemm_mfma<128, 128, 128, 128, 128, 64, 64, 1, 64, 64>
        <<<dim3(GM, 1), 256, 0, stream>>>(
        s_x1, nullptr, nullptr, 128, 0, 0, wt2h, wt2l, sk2b,
        s_xh, s_h2, 64, 64, s_als, s_ald, as2, ad2, NN);
    node_agg_kernel<1, 64, false><<<(NN + 3) / 4, 256, 0, stream>>>(
        i_rowptr, i_csrsrc, s_xh, s_als, s_ald, b2, s_h2, s_h2, NN);

    // ======= JumpingKnowledge: out = [x0|x1|h2] @ jkW + jkb (K=320, N=64)
    gemm_mfma<320, 64, 64, 128, 256, 64, 0, 0, 16, 0>
        <<<dim3(GM, 1), 256, 0, stream>>>(
        s_x0, s_x1, s_h2, 128, 128, 64, wtjh, wtjl, jkb,
        out, nullptr, 64, 0, nullptr, nullptr, nullptr, nullptr, NN);
}

// Round 3
// 666.100 us; speedup vs baseline: 1.5109x; 1.2548x over previous
//
#include <hip/hip_runtime.h>
#include <hip/hip_bf16.h>
#include <cstdint>

static constexpr int NN = 100000;     // nodes
static constexpr int NE = 800000;     // edges (without self loops)
static constexpr int EP = NE + NN;    // edges incl. self loops
static constexpr int NB = (NN + 255) / 256;  // scan blocks

typedef unsigned short ushort;
typedef __attribute__((ext_vector_type(8))) short short8;
typedef __attribute__((ext_vector_type(8))) ushort ushort8v;
typedef __attribute__((ext_vector_type(4))) ushort ushort4v;
typedef __attribute__((ext_vector_type(4))) float f32x4;

__device__ __forceinline__ float leaky(float x) { return x > 0.f ? x : 0.2f * x; }

// float -> bf16 bits (RNE)
__device__ __forceinline__ ushort f2bf(float f) {
    unsigned int u = __float_as_uint(f);
    u += 0x7fffu + ((u >> 16) & 1u);
    return (ushort)(u >> 16);
}
__device__ __forceinline__ float bf2f(ushort h) {
    return __uint_as_float(((unsigned int)h) << 16);
}

// ---------------------------------------------------------------------------
// Weight pre-tiling: W (virtual concat [Wa | Wb], K x NT, row-major) ->
//   Whi/Wlo: [K/32][NT][32] bf16 (hi + lo split).  Tiny, runs once per layer.
// ---------------------------------------------------------------------------
__global__ void pretile_kernel(const float* __restrict__ Wa, const float* __restrict__ Wb,
                               int K, int CS, int NT,
                               ushort* __restrict__ Whi, ushort* __restrict__ Wlo)
{
    int idx = blockIdx.x * 256 + threadIdx.x;
    if (idx >= K * NT) return;
    int k = idx / NT, c = idx - k * NT;
    float v = (c < CS) ? Wa[(size_t)k * CS + c] : Wb[(size_t)k * (NT - CS) + (c - CS)];
    ushort h = f2bf(v);
    ushort l = f2bf(v - bf2f(h));
    size_t o = ((size_t)(k >> 5) * NT + c) * 32 + (k & 31);
    Whi[o] = h; Wlo[o] = l;
}

// ---------------------------------------------------------------------------
// Split-bf16 MFMA GEMM (3-pass hi/lo emulation, ~fp32 accuracy).
// Block: 256 thr (2x2 waves), tile 128 rows x NCB cols; grid.y = NTOT/NCB.
// ---------------------------------------------------------------------------
template<int KTOT, int NTOT, int NCB, int K1, int K2, int CSPLIT, int BIAS_OFF,
         int AHH, int ACC, int ATTN>
__global__ __launch_bounds__(256, 3)
void gemm_mfma(const float* __restrict__ X1, const float* __restrict__ X2,
               const float* __restrict__ X3, int ldx1, int ldx2, int ldx3,
               const ushort* __restrict__ Wthi, const ushort* __restrict__ Wtlo,
               const float* __restrict__ bias,
               float* __restrict__ Y1, float* __restrict__ Y2, int ldy1, int ldy2,
               float* __restrict__ als, float* __restrict__ ald,
               const float* __restrict__ a_src, const float* __restrict__ a_dst,
               int n)
{
    constexpr int NH  = NCB / 2;      // cols per wave
    constexpr int NF  = NH / 16;      // 16-wide col frags per wave
    constexpr int NKT = KTOT / 32;    // K tiles

    __shared__ ushort Ahi[128][40], Alo[128][40];
    __shared__ ushort Bhi[NCB][40], Blo[NCB][40];

    const int t  = threadIdx.x;
    const int l  = t & 63, w = t >> 6;
    const int wm = w >> 1, wc = w & 1;          // 2x2 wave grid
    const int lc = l & 15, lq = l >> 4;
    const int bm = blockIdx.x * 128;
    const int cbase = blockIdx.y * NCB;         // global col base of block
    const int colb = wc * NH;                   // wave col base within block

    f32x4 acc[4][NF];
#pragma unroll
    for (int mf = 0; mf < 4; ++mf)
#pragma unroll
        for (int nf = 0; nf < NF; ++nf)
            acc[mf][nf] = (f32x4){0.f, 0.f, 0.f, 0.f};

    const int kq = (t & 7) * 4;       // k offset for A staging (float4)
    const int rb = t >> 3;            // row 0..31 per pass

    for (int kt = 0; kt < NKT; ++kt) {
        const int k0 = kt * 32;
        const float* xp; int ldx, koff;
        if (k0 < K1)      { xp = X1; ldx = ldx1; koff = k0; }
        else if (k0 < K2) { xp = X2; ldx = ldx2; koff = k0 - K1; }
        else              { xp = X3; ldx = ldx3; koff = k0 - K2; }

        // ---- stage A: 128 rows x 32 k, f32 -> bf16 hi/lo ----
#pragma unroll
        for (int p = 0; p < 4; ++p) {
            int rr = rb + p * 32;
            int gr = bm + rr;
            float4 v = make_float4(0.f, 0.f, 0.f, 0.f);
            if (gr < n) v = *(const float4*)&xp[(size_t)gr * ldx + koff + kq];
            ushort4v hh, ll;
            const float* vp = &v.x;
#pragma unroll
            for (int e = 0; e < 4; ++e) {
                ushort h = f2bf(vp[e]);
                hh[e] = h;
                ll[e] = f2bf(vp[e] - bf2f(h));
            }
            *(ushort4v*)&Ahi[rr][kq] = hh;
            *(ushort4v*)&Alo[rr][kq] = ll;
        }

        // ---- stage B: pre-tiled bf16 copy [NCB][32] -> LDS ----
        {
            const ushort* wb0 = &Wthi[((size_t)kt * NTOT + cbase) * 32];
            const ushort* wb1 = &Wtlo[((size_t)kt * NTOT + cbase) * 32];
#pragma unroll
            for (int ii = 0; ii < NCB / 64; ++ii) {
                int i = t + ii * 256;
                int nn = i >> 2, q = (i & 3) * 8;
                *(ushort8v*)&Bhi[nn][q] = *(const ushort8v*)&wb0[nn * 32 + q];
                *(ushort8v*)&Blo[nn][q] = *(const ushort8v*)&wb1[nn * 32 + q];
            }
        }
        __syncthreads();

        // ---- MFMA inner: 3 passes (hi*hi + hi*lo + lo*hi) ----
        short8 ah[4], alv[4];
#pragma unroll
        for (int mf = 0; mf < 4; ++mf) {
            ah[mf]  = *(const short8*)&Ahi[wm * 64 + mf * 16 + lc][lq * 8];
            alv[mf] = *(const short8*)&Alo[wm * 64 + mf * 16 + lc][lq * 8];
        }
#pragma unroll
        for (int nf = 0; nf < NF; ++nf) {
            short8 bh = *(const short8*)&Bhi[colb + nf * 16 + lc][lq * 8];
            short8 bl = *(const short8*)&Blo[colb + nf * 16 + lc][lq * 8];
#pragma unroll
            for (int mf = 0; mf < 4; ++mf) {
                acc[mf][nf] = __builtin_amdgcn_mfma_f32_16x16x32_bf16(ah[mf],  bh, acc[mf][nf], 0, 0, 0);
                acc[mf][nf] = __builtin_amdgcn_mfma_f32_16x16x32_bf16(ah[mf],  bl, acc[mf][nf], 0, 0, 0);
                acc[mf][nf] = __builtin_amdgcn_mfma_f32_16x16x32_bf16(alv[mf], bh, acc[mf][nf], 0, 0, 0);
            }
        }
        __syncthreads();
    }

    // ---- attention-logit epilogue (MFMA layout: col = lc, rows = lq*4+r) ----
    if constexpr (AHH > 0) {
        if (cbase == 0) {
            constexpr int FPH = ACC / 16;     // frags per head
            constexpr int NG  = NF / FPH;     // head groups per wave
#pragma unroll
            for (int g = 0; g < NG; ++g) {
                if (colb + g * ACC < ATTN) {
#pragma unroll
                    for (int mf = 0; mf < 4; ++mf) {
                        float ps[4] = {0.f, 0.f, 0.f, 0.f};
                        float pd[4] = {0.f, 0.f, 0.f, 0.f};
#pragma unroll
                        for (int j = 0; j < FPH; ++j) {
                            int col = colb + g * ACC + j * 16 + lc;
                            float av = a_src[col], dv = a_dst[col];
#pragma unroll
                            for (int r = 0; r < 4; ++r) {
                                ps[r] = fmaf(acc[mf][g * FPH + j][r], av, ps[r]);
                                pd[r] = fmaf(acc[mf][g * FPH + j][r], dv, pd[r]);
                            }
                        }
#pragma unroll
                        for (int off = 1; off < 16; off <<= 1)
#pragma unroll
                            for (int r = 0; r < 4; ++r) {
                                ps[r] += __shfl_xor(ps[r], off);
                                pd[r] += __shfl_xor(pd[r], off);
                            }
                        if (lc == 0) {
                            int h = (colb + g * ACC) / ACC;
#pragma unroll
                            for (int r = 0; r < 4; ++r) {
                                int row = bm + wm * 64 + mf * 16 + lq * 4 + r;
                                if (row < n) {
                                    als[(size_t)row * AHH + h] = ps[r];
                                    ald[(size_t)row * AHH + h] = pd[r];
                                }
                            }
                        }
                    }
                }
            }
        }
    }

    // ---- store (+ bias for cols >= BIAS_OFF) ----
#pragma unroll
    for (int mf = 0; mf < 4; ++mf) {
        int rowb = bm + wm * 64 + mf * 16 + lq * 4;
#pragma unroll
        for (int nf = 0; nf < NF; ++nf) {
            int col = cbase + colb + nf * 16 + lc;
            float bv = 0.f;
            if constexpr (BIAS_OFF < NTOT) {
                if (col >= BIAS_OFF) bv = bias[col - BIAS_OFF];
            }
#pragma unroll
            for (int r = 0; r < 4; ++r) {
                int row = rowb + r;
                if (row < n) {
                    float v = acc[mf][nf][r] + bv;
                    if (col < CSPLIT)
                        Y1[(size_t)row * ldy1 + col] = v;
                    else
                        Y2[(size_t)row * ldy2 + (col - CSPLIT)] = v;
                }
            }
        }
    }
}

// ---------------------------------------------------------------------------
// CSR build: histogram -> block sums -> scan sums -> per-block scan -> fill
// ---------------------------------------------------------------------------
__global__ void deg_kernel(const int* __restrict__ ei, int* __restrict__ deg)
{
    int t = blockIdx.x * blockDim.x + threadIdx.x;
    if (t < NE) atomicAdd(&deg[ei[NE + t]], 1);   // dst of edge t
}

__global__ void block_sum_kernel(const int* __restrict__ deg, int* __restrict__ bsum)
{
    int node = blockIdx.x * 256 + threadIdx.x;
    int v = (node < NN) ? deg[node] + 1 : 0;      // +1 = self loop
#pragma unroll
    for (int off = 32; off > 0; off >>= 1) v += __shfl_down(v, off);
    __shared__ int sh[4];
    if ((threadIdx.x & 63) == 0) sh[threadIdx.x >> 6] = v;
    __syncthreads();
    if (threadIdx.x == 0) bsum[blockIdx.x] = sh[0] + sh[1] + sh[2] + sh[3];
}

__global__ void scan_sums_kernel(const int* __restrict__ bsum, int* __restrict__ bsumx,
                                 int* __restrict__ rowptr)
{
    if (threadIdx.x == 0) {
        int run = 0;
        for (int i = 0; i < NB; ++i) { bsumx[i] = run; run += bsum[i]; }
        rowptr[NN] = run;    // == EP
    }
}

__global__ void scan_blocks_kernel(const int* __restrict__ deg, const int* __restrict__ bsumx,
                                   int* __restrict__ rowptr, int* __restrict__ cursor)
{
    __shared__ int sh[256];
    int node = blockIdx.x * 256 + threadIdx.x;
    int v = (node < NN) ? deg[node] + 1 : 0;
    sh[threadIdx.x] = v;
    __syncthreads();
#pragma unroll
    for (int off = 1; off < 256; off <<= 1) {
        int tv = (threadIdx.x >= off) ? sh[threadIdx.x - off] : 0;
        __syncthreads();
        sh[threadIdx.x] += tv;
        __syncthreads();
    }
    if (node < NN) {
        int excl = bsumx[blockIdx.x] + sh[threadIdx.x] - v;
        rowptr[node] = excl;
        cursor[node] = excl;
    }
}

__global__ void fill_kernel(const int* __restrict__ ei, int* __restrict__ cursor,
                            int* __restrict__ csr_src)
{
    int t = blockIdx.x * blockDim.x + threadIdx.x;
    if (t >= EP) return;
    int s, d;
    if (t < NE) { s = ei[t]; d = ei[NE + t]; }
    else        { s = d = t - NE; }
    int pos = atomicAdd(&cursor[d], 1);
    csr_src[pos] = s;
}

// ---------------------------------------------------------------------------
// Softmax stats + normalized edge weights. ONE THREAD PER NODE (the serial
// online-softmax chain lives here only, deg~9 iterations, scalar).
//   wq[e*HH+h] = exp(leaky(als[src,h]+ald[node,h]) - m[h]) / denom[h]
// ---------------------------------------------------------------------------
template<int HH>
__global__ __launch_bounds__(256)
void attn_weights_kernel(const int* __restrict__ rowptr, const int* __restrict__ csr_src,
                         const float* __restrict__ als, const float* __restrict__ ald,
                         float* __restrict__ wq, int n)
{
    int node = blockIdx.x * 256 + threadIdx.x;
    if (node >= n) return;
    const int e0 = rowptr[node], e1 = rowptr[node + 1];
    float aldv[HH], m[HH], d[HH];
#pragma unroll
    for (int h = 0; h < HH; ++h) { m[h] = -1e30f; d[h] = 0.f; }
    if constexpr (HH == 4) {
        float4 a = *(const float4*)&ald[(size_t)node * 4];
        aldv[0] = a.x; aldv[1] = a.y; aldv[2] = a.z; aldv[3] = a.w;
    } else {
        aldv[0] = ald[node];
    }
    for (int e = e0; e < e1; ++e) {
        int s = csr_src[e];
        float av[HH];
        if constexpr (HH == 4) {
            float4 a = *(const float4*)&als[(size_t)s * 4];
            av[0] = a.x; av[1] = a.y; av[2] = a.z; av[3] = a.w;
        } else {
            av[0] = als[s];
        }
#pragma unroll
        for (int h = 0; h < HH; ++h) {
            float sc = leaky(av[h] + aldv[h]);
            float nm = fmaxf(m[h], sc);
            d[h] = d[h] * __expf(m[h] - nm) + __expf(sc - nm);
            m[h] = nm;
        }
    }
#pragma unroll
    for (int h = 0; h < HH; ++h) d[h] = 1.f / d[h];
    for (int e = e0; e < e1; ++e) {
        int s = csr_src[e];
        float av[HH];
        if constexpr (HH == 4) {
            float4 a = *(const float4*)&als[(size_t)s * 4];
            av[0] = a.x; av[1] = a.y; av[2] = a.z; av[3] = a.w;
        } else {
            av[0] = als[s];
        }
        float wv[HH];
#pragma unroll
        for (int h = 0; h < HH; ++h)
            wv[h] = __expf(leaky(av[h] + aldv[h]) - m[h]) * d[h];
        if constexpr (HH == 4) {
            float4 o; o.x = wv[0]; o.y = wv[1]; o.z = wv[2]; o.w = wv[3];
            *(float4*)&wq[(size_t)e * 4] = o;
        } else {
            wq[e] = wv[0];
        }
    }
}

// ---------------------------------------------------------------------------
// Weighted gather-SpMM + fused epilogue. ONE WAVE PER NODE, lane = channel
// pair. Pure independent FMA accumulation (no softmax chain), 2-way edge
// unroll for load-level parallelism.
// ---------------------------------------------------------------------------
template<int HH, int CC, bool DOELU>
__global__ __launch_bounds__(256)
void spmm_kernel(const int* __restrict__ rowptr, const int* __restrict__ csr_src,
                 const float* __restrict__ xh, const float* __restrict__ wq,
                 const float* __restrict__ b, const float* __restrict__ res,
                 float* __restrict__ out, int n)
{
    constexpr int HCL = HH * CC;
    constexpr int CPL = HCL / 64;                 // channels per lane (2 or 1)
    const int l = threadIdx.x & 63;
    const int node = blockIdx.x * 4 + (threadIdx.x >> 6);
    if (node >= n) return;
    const int c = l * CPL;
    const int h = c / CC;
    const int e0 = rowptr[node], e1 = rowptr[node + 1];

    float a0[CPL], a1[CPL];
#pragma unroll
    for (int j = 0; j < CPL; ++j) { a0[j] = 0.f; a1[j] = 0.f; }

    int e = e0;
    for (; e + 1 < e1; e += 2) {
        int s0 = csr_src[e], s1 = csr_src[e + 1];
        float w0 = wq[(size_t)e * HH + h];
        float w1 = wq[(size_t)(e + 1) * HH + h];
        if constexpr (CPL == 2) {
            float2 x0 = *(const float2*)&xh[(size_t)s0 * HCL + c];
            float2 x1 = *(const float2*)&xh[(size_t)s1 * HCL + c];
            a0[0] = fmaf(w0, x0.x, a0[0]); a0[1] = fmaf(w0, x0.y, a0[1]);
            a1[0] = fmaf(w1, x1.x, a1[0]); a1[1] = fmaf(w1, x1.y, a1[1]);
        } else {
            a0[0] = fmaf(w0, xh[(size_t)s0 * HCL + c], a0[0]);
            a1[0] = fmaf(w1, xh[(size_t)s1 * HCL + c], a1[0]);
        }
    }
    if (e < e1) {
        int s0 = csr_src[e];
        float w0 = wq[(size_t)e * HH + h];
        if constexpr (CPL == 2) {
            float2 x0 = *(const float2*)&xh[(size_t)s0 * HCL + c];
            a0[0] = fmaf(w0, x0.x, a0[0]); a0[1] = fmaf(w0, x0.y, a0[1]);
        } else {
            a0[0] = fmaf(w0, xh[(size_t)s0 * HCL + c], a0[0]);
        }
    }

#pragma unroll
    for (int j = 0; j < CPL; ++j) {
        float v = a0[j] + a1[j] + b[c + j] + res[(size_t)node * HCL + c + j];
        if (DOELU) v = v > 0.f ? v : (__expf(v) - 1.f);
        out[(size_t)node * HCL + c + j] = v;
    }
}

// ---------------------------------------------------------------------------
extern "C" void kernel_launch(void* const* d_in, const int* in_sizes, int n_in,
                              void* d_out, int out_size, void* d_ws, size_t ws_size,
                              hipStream_t stream)
{
    const float* x    = (const float*)d_in[0];
    const int*   ei   = (const int*)d_in[1];
    const float* W0   = (const float*)d_in[2];
    const float* b0   = (const float*)d_in[3];
    const float* as0  = (const float*)d_in[4];
    const float* ad0  = (const float*)d_in[5];
    const float* W1   = (const float*)d_in[6];
    const float* b1   = (const float*)d_in[7];
    const float* as1  = (const float*)d_in[8];
    const float* ad1  = (const float*)d_in[9];
    const float* W2   = (const float*)d_in[10];
    const float* b2   = (const float*)d_in[11];
    const float* as2  = (const float*)d_in[12];
    const float* ad2  = (const float*)d_in[13];
    const float* sk0W = (const float*)d_in[14];
    const float* sk0b = (const float*)d_in[15];
    const float* sk2W = (const float*)d_in[16];
    const float* sk2b = (const float*)d_in[17];
    const float* jkW  = (const float*)d_in[18];
    const float* jkb  = (const float*)d_in[19];
    float* out = (float*)d_out;

    float* ws = (float*)d_ws;
    size_t off = 0;
    float* s_x0  = ws + off; off += (size_t)NN * 128;
    float* s_x1  = ws + off; off += (size_t)NN * 128;
    float* s_h2  = ws + off; off += (size_t)NN * 64;
    float* s_xh  = ws + off; off += (size_t)NN * 128;
    float* s_als = ws + off; off += (size_t)NN * 4;
    float* s_ald = ws + off; off += (size_t)NN * 4;
    float* f_wq  = ws + off; off += (size_t)EP * 4;
    int* i_deg    = (int*)(ws + off); off += NN;
    int* i_rowptr = (int*)(ws + off); off += NN + 1;
    int* i_cursor = (int*)(ws + off); off += NN;
    int* i_csrsrc = (int*)(ws + off); off += EP;
    int* i_bsum   = (int*)(ws + off); off += NB;
    int* i_bsumx  = (int*)(ws + off); off += NB;
    off = (off + 3) & ~(size_t)3;     // 16B-align the bf16 weight tiles
    // pre-tiled split-bf16 weights: [K/32][NT][32] u16 each (hi, lo)
    ushort* wt0h = (ushort*)(ws + off); off += 32768;   // 8*256*32 u16
    ushort* wt0l = (ushort*)(ws + off); off += 32768;
    ushort* wt1h = (ushort*)(ws + off); off += 8192;    // 4*128*32 u16
    ushort* wt1l = (ushort*)(ws + off); off += 8192;
    ushort* wt2h = (ushort*)(ws + off); off += 8192;    // 4*128*32 u16
    ushort* wt2l = (ushort*)(ws + off); off += 8192;
    ushort* wtjh = (ushort*)(ws + off); off += 10240;   // 10*64*32 u16
    ushort* wtjl = (ushort*)(ws + off); off += 10240;

    const int GM = (NN + 127) / 128;    // 782 row blocks
    const int GN = (NN + 255) / 256;    // node-thread blocks
    const int GS = (NN + 3) / 4;        // node-wave blocks
    constexpr int BIG = 1 << 30;

    // ======================= CSR build (shared by all 3 layers) ==========
    hipMemsetAsync(i_deg, 0, (size_t)NN * sizeof(int), stream);
    deg_kernel<<<(NE + 255) / 256, 256, 0, stream>>>(ei, i_deg);
    block_sum_kernel<<<NB, 256, 0, stream>>>(i_deg, i_bsum);
    scan_sums_kernel<<<1, 64, 0, stream>>>(i_bsum, i_bsumx, i_rowptr);
    scan_blocks_kernel<<<NB, 256, 0, stream>>>(i_deg, i_bsumx, i_rowptr, i_cursor);
    fill_kernel<<<(EP + 255) / 256, 256, 0, stream>>>(ei, i_cursor, i_csrsrc);

    // ======================= weight pre-tiling (split bf16) ==============
    pretile_kernel<<<256, 256, 0, stream>>>(W0, sk0W, 256, 128, 256, wt0h, wt0l);
    pretile_kernel<<<64,  256, 0, stream>>>(W1, nullptr, 128, 128, 128, wt1h, wt1l);
    pretile_kernel<<<64,  256, 0, stream>>>(W2, sk2W, 128, 64, 128, wt2h, wt2l);
    pretile_kernel<<<80,  256, 0, stream>>>(jkW, nullptr, 320, 64, 64, wtjh, wtjl);

    // ======= layer 0: fused [xh0 | res0] = x @ [W0 | sk0W] (K=256, N=256)
    gemm_mfma<256, 256, 128, 256, 256, 128, 128, 4, 32, 128>
        <<<dim3(GM, 2), 256, 0, stream>>>(
        x, nullptr, nullptr, 256, 0, 0, wt0h, wt0l, sk0b,
        s_xh, s_x0, 128, 128, s_als, s_ald, as0, ad0, NN);
    attn_weights_kernel<4><<<GN, 256, 0, stream>>>(
        i_rowptr, i_csrsrc, s_als, s_ald, f_wq, NN);
    spmm_kernel<4, 32, true><<<GS, 256, 0, stream>>>(
        i_rowptr, i_csrsrc, s_xh, f_wq, b0, s_x0, s_x0, NN);

    // ======= layer 1: xh1 = x0 @ W1 (K=128, N=128, no bias in GEMM)
    gemm_mfma<128, 128, 128, 128, 128, 128, BIG, 4, 32, 128>
        <<<dim3(GM, 1), 256, 0, stream>>>(
        s_x0, nullptr, nullptr, 128, 0, 0, wt1h, wt1l, nullptr,
        s_xh, nullptr, 128, 0, s_als, s_ald, as1, ad1, NN);
    attn_weights_kernel<4><<<GN, 256, 0, stream>>>(
        i_rowptr, i_csrsrc, s_als, s_ald, f_wq, NN);
    spmm_kernel<4, 32, true><<<GS, 256, 0, stream>>>(
        i_rowptr, i_csrsrc, s_xh, f_wq, b1, s_x0, s_x1, NN);

    // ======= layer 2: fused [xh2 | res2] = x1 @ [W2 | sk2W] (K=128, N=128)
    gemm_mfma<128, 128, 128, 128, 128, 64, 64, 1, 64, 64>
        <<<dim3(GM, 1), 256, 0, stream>>>(
        s_x1, nullptr, nullptr, 128, 0, 0, wt2h, wt2l, sk2b,
        s_xh, s_h2, 64, 64, s_als, s_ald, as2, ad2, NN);
    attn_weights_kernel<1><<<GN, 256, 0, stream>>>(
        i_rowptr, i_csrsrc, s_als, s_ald, f_wq, NN);
    spmm_kernel<1, 64, false><<<GS, 256, 0, stream>>>(
        i_rowptr, i_csrsrc, s_xh, f_wq, b2, s_h2, s_h2, NN);

    // ======= JumpingKnowledge: out = [x0|x1|h2] @ jkW + jkb (K=320, N=64)
    gemm_mfma<320, 64, 64, 128, 256, 64, 0, 0, 16, 0>
        <<<dim3(GM, 1), 256, 0, stream>>>(
        s_x0, s_x1, s_h2, 128, 128, 64, wtjh, wtjl, jkb,
        out, nullptr, 64, 0, nullptr, nullptr, nullptr, nullptr, NN);
}

// Round 4
// 651.052 us; speedup vs baseline: 1.5458x; 1.0231x over previous
//
#include <hip/hip_runtime.h>
#include <hip/hip_bf16.h>
#include <cstdint>

static constexpr int NN = 100000;     // nodes
static constexpr int NE = 800000;     // edges (without self loops)
static constexpr int EP = NE + NN;    // edges incl. self loops
static constexpr int NB = (NN + 255) / 256;  // scan blocks

typedef unsigned short ushort;
typedef __attribute__((ext_vector_type(8))) short short8;
typedef __attribute__((ext_vector_type(8))) ushort ushort8v;
typedef __attribute__((ext_vector_type(4))) ushort ushort4v;
typedef __attribute__((ext_vector_type(4))) float f32x4;

__device__ __forceinline__ float leaky(float x) { return x > 0.f ? x : 0.2f * x; }

// float -> bf16 bits (RNE)
__device__ __forceinline__ ushort f2bf(float f) {
    unsigned int u = __float_as_uint(f);
    u += 0x7fffu + ((u >> 16) & 1u);
    return (ushort)(u >> 16);
}
__device__ __forceinline__ float bf2f(ushort h) {
    return __uint_as_float(((unsigned int)h) << 16);
}

// ---------------------------------------------------------------------------
// Weight pre-tiling: W (virtual concat [Wa | Wb], K x NT, row-major) ->
//   Whi/Wlo: [K/32][NT][32] bf16 (hi + lo split).  Tiny, runs once per layer.
// ---------------------------------------------------------------------------
__global__ void pretile_kernel(const float* __restrict__ Wa, const float* __restrict__ Wb,
                               int K, int CS, int NT,
                               ushort* __restrict__ Whi, ushort* __restrict__ Wlo)
{
    int idx = blockIdx.x * 256 + threadIdx.x;
    if (idx >= K * NT) return;
    int k = idx / NT, c = idx - k * NT;
    float v = (c < CS) ? Wa[(size_t)k * CS + c] : Wb[(size_t)k * (NT - CS) + (c - CS)];
    ushort h = f2bf(v);
    ushort l = f2bf(v - bf2f(h));
    size_t o = ((size_t)(k >> 5) * NT + c) * 32 + (k & 31);
    Whi[o] = h; Wlo[o] = l;
}

// ---------------------------------------------------------------------------
// Split-bf16 MFMA GEMM (3-pass hi/lo emulation, ~fp32 accuracy), software-
// pipelined: tile k+1 global loads are issued BEFORE tile k's MFMA phase
// (reg prefetch), converted/committed to LDS after the post-compute barrier.
//   ASPLIT=false: X sources are f32 (converted on the fly).
//   ASPLIT=true : X sources are pre-split hi/lo bf16 arrays (pure copies).
// Block: 256 thr (2x2 waves), tile 128 rows x NCB cols; grid.y = NTOT/NCB.
// MFMA 16x16x32 bf16 layouts (m89/m91-verified):
//   A: lane l holds A[l&15][8*(l>>4)+e]; B: lane l holds B[8*(l>>4)+e][l&15]
//   D: lane l reg r = D[(l>>4)*4+r][l&15]
// ---------------------------------------------------------------------------
template<int KTOT, int NTOT, int NCB, int K1, int K2, int CSPLIT, int BIAS_OFF,
         int AHH, int ACC, int ATTN, bool ASPLIT>
__global__ __launch_bounds__(256, 3)
void gemm_mfma(const void* __restrict__ X1, const void* __restrict__ X1b,
               const void* __restrict__ X2, const void* __restrict__ X2b,
               const void* __restrict__ X3, const void* __restrict__ X3b,
               int ldx1, int ldx2, int ldx3,
               const ushort* __restrict__ Wthi, const ushort* __restrict__ Wtlo,
               const float* __restrict__ bias,
               float* __restrict__ Y1, float* __restrict__ Y2, int ldy1, int ldy2,
               float* __restrict__ als, float* __restrict__ ald,
               const float* __restrict__ a_src, const float* __restrict__ a_dst,
               int n)
{
    constexpr int NH  = NCB / 2;      // cols per wave
    constexpr int NF  = NH / 16;      // 16-wide col frags per wave
    constexpr int NKT = KTOT / 32;    // K tiles

    __shared__ ushort Ahi[128][40], Alo[128][40];   // 40 = 32 + pad (16B rows)
    __shared__ ushort Bhi[NCB][40], Blo[NCB][40];

    const int t  = threadIdx.x;
    const int l  = t & 63, w = t >> 6;
    const int wm = w >> 1, wc = w & 1;          // 2x2 wave grid
    const int lc = l & 15, lq = l >> 4;
    const int bm = blockIdx.x * 128;
    const int cbase = blockIdx.y * NCB;         // global col base of block
    const int colb = wc * NH;                   // wave col base within block

    f32x4 acc[4][NF];
#pragma unroll
    for (int mf = 0; mf < 4; ++mf)
#pragma unroll
        for (int nf = 0; nf < NF; ++nf)
            acc[mf][nf] = (f32x4){0.f, 0.f, 0.f, 0.f};

    // staging coords
    const int kqf = (t & 7) * 4;      // f32 path: float offset in k
    const int rbf = t >> 3;           // f32 path: row 0..31 (+p*32)
    const int kqs = (t & 3) * 8;      // split path: u16 offset in k
    const int rbs = t >> 2;           // split path: row 0..63 (+p*64)

    float4   pa[4];                   // prefetch regs (f32 path)
    ushort8v pah[2], pal[2];          // prefetch regs (split path)
    ushort8v pbh[NCB / 64], pbl[NCB / 64];

    auto issue = [&](int kt) {
        const int k0 = kt * 32;
        const void* xp; const void* xq; int ldx, koff;
        if (k0 < K1)      { xp = X1; xq = X1b; ldx = ldx1; koff = k0; }
        else if (k0 < K2) { xp = X2; xq = X2b; ldx = ldx2; koff = k0 - K1; }
        else              { xp = X3; xq = X3b; ldx = ldx3; koff = k0 - K2; }
        if constexpr (ASPLIT) {
            const ushort* ph = (const ushort*)xp;
            const ushort* pl = (const ushort*)xq;
#pragma unroll
            for (int p = 0; p < 2; ++p) {
                int gr = bm + rbs + p * 64;
                ushort8v zh = {0,0,0,0,0,0,0,0};
                ushort8v zl = {0,0,0,0,0,0,0,0};
                if (gr < n) {
                    size_t o = (size_t)gr * ldx + koff + kqs;
                    zh = *(const ushort8v*)&ph[o];
                    zl = *(const ushort8v*)&pl[o];
                }
                pah[p] = zh; pal[p] = zl;
            }
        } else {
            const float* pf = (const float*)xp;
#pragma unroll
            for (int p = 0; p < 4; ++p) {
                int gr = bm + rbf + p * 32;
                pa[p] = make_float4(0.f, 0.f, 0.f, 0.f);
                if (gr < n) pa[p] = *(const float4*)&pf[(size_t)gr * ldx + koff + kqf];
            }
        }
        const ushort* wb0 = &Wthi[((size_t)kt * NTOT + cbase) * 32];
        const ushort* wb1 = &Wtlo[((size_t)kt * NTOT + cbase) * 32];
#pragma unroll
        for (int ii = 0; ii < NCB / 64; ++ii) {
            int i = t + ii * 256;
            int nn = i >> 2, q = (i & 3) * 8;
            pbh[ii] = *(const ushort8v*)&wb0[nn * 32 + q];
            pbl[ii] = *(const ushort8v*)&wb1[nn * 32 + q];
        }
    };

    auto commit = [&]() {
        if constexpr (ASPLIT) {
#pragma unroll
            for (int p = 0; p < 2; ++p) {
                int rr = rbs + p * 64;
                *(ushort8v*)&Ahi[rr][kqs] = pah[p];
                *(ushort8v*)&Alo[rr][kqs] = pal[p];
            }
        } else {
#pragma unroll
            for (int p = 0; p < 4; ++p) {
                int rr = rbf + p * 32;
                ushort4v hh, ll;
                const float* vp = &pa[p].x;
#pragma unroll
                for (int e = 0; e < 4; ++e) {
                    ushort h = f2bf(vp[e]);
                    hh[e] = h;
                    ll[e] = f2bf(vp[e] - bf2f(h));
                }
                *(ushort4v*)&Ahi[rr][kqf] = hh;
                *(ushort4v*)&Alo[rr][kqf] = ll;
            }
        }
#pragma unroll
        for (int ii = 0; ii < NCB / 64; ++ii) {
            int i = t + ii * 256;
            int nn = i >> 2, q = (i & 3) * 8;
            *(ushort8v*)&Bhi[nn][q] = pbh[ii];
            *(ushort8v*)&Blo[nn][q] = pbl[ii];
        }
    };

    issue(0);
    commit();
    __syncthreads();

    for (int kt = 0; kt < NKT; ++kt) {
        const bool more = (kt + 1 < NKT);
        if (more) issue(kt + 1);          // loads in flight across compute

        // ---- MFMA inner: 3 passes (hi*hi + hi*lo + lo*hi) ----
        short8 ah[4], alv[4];
#pragma unroll
        for (int mf = 0; mf < 4; ++mf) {
            ah[mf]  = *(const short8*)&Ahi[wm * 64 + mf * 16 + lc][lq * 8];
            alv[mf] = *(const short8*)&Alo[wm * 64 + mf * 16 + lc][lq * 8];
        }
#pragma unroll
        for (int nf = 0; nf < NF; ++nf) {
            short8 bh = *(const short8*)&Bhi[colb + nf * 16 + lc][lq * 8];
            short8 bl = *(const short8*)&Blo[colb + nf * 16 + lc][lq * 8];
#pragma unroll
            for (int mf = 0; mf < 4; ++mf) {
                acc[mf][nf] = __builtin_amdgcn_mfma_f32_16x16x32_bf16(ah[mf],  bh, acc[mf][nf], 0, 0, 0);
                acc[mf][nf] = __builtin_amdgcn_mfma_f32_16x16x32_bf16(ah[mf],  bl, acc[mf][nf], 0, 0, 0);
                acc[mf][nf] = __builtin_amdgcn_mfma_f32_16x16x32_bf16(alv[mf], bh, acc[mf][nf], 0, 0, 0);
            }
        }
        __syncthreads();                  // all waves done reading tile kt
        if (more) {
            commit();                     // write tile kt+1 into LDS
            __syncthreads();
        }
    }

    // ---- attention-logit epilogue (MFMA layout: col = lc, rows = lq*4+r) ----
    if constexpr (AHH > 0) {
        if (cbase == 0) {
            constexpr int FPH = ACC / 16;     // frags per head
            constexpr int NG  = NF / FPH;     // head groups per wave
#pragma unroll
            for (int g = 0; g < NG; ++g) {
                if (colb + g * ACC < ATTN) {
#pragma unroll
                    for (int mf = 0; mf < 4; ++mf) {
                        float ps[4] = {0.f, 0.f, 0.f, 0.f};
                        float pd[4] = {0.f, 0.f, 0.f, 0.f};
#pragma unroll
                        for (int j = 0; j < FPH; ++j) {
                            int col = colb + g * ACC + j * 16 + lc;
                            float av = a_src[col], dv = a_dst[col];
#pragma unroll
                            for (int r = 0; r < 4; ++r) {
                                ps[r] = fmaf(acc[mf][g * FPH + j][r], av, ps[r]);
                                pd[r] = fmaf(acc[mf][g * FPH + j][r], dv, pd[r]);
                            }
                        }
#pragma unroll
                        for (int off = 1; off < 16; off <<= 1)
#pragma unroll
                            for (int r = 0; r < 4; ++r) {
                                ps[r] += __shfl_xor(ps[r], off);
                                pd[r] += __shfl_xor(pd[r], off);
                            }
                        if (lc == 0) {
                            int h = (colb + g * ACC) / ACC;
#pragma unroll
                            for (int r = 0; r < 4; ++r) {
                                int row = bm + wm * 64 + mf * 16 + lq * 4 + r;
                                if (row < n) {
                                    als[(size_t)row * AHH + h] = ps[r];
                                    ald[(size_t)row * AHH + h] = pd[r];
                                }
                            }
                        }
                    }
                }
            }
        }
    }

    // ---- store (+ bias for cols >= BIAS_OFF) ----
#pragma unroll
    for (int mf = 0; mf < 4; ++mf) {
        int rowb = bm + wm * 64 + mf * 16 + lq * 4;
#pragma unroll
        for (int nf = 0; nf < NF; ++nf) {
            int col = cbase + colb + nf * 16 + lc;
            float bv = 0.f;
            if constexpr (BIAS_OFF < NTOT) {
                if (col >= BIAS_OFF) bv = bias[col - BIAS_OFF];
            }
#pragma unroll
            for (int r = 0; r < 4; ++r) {
                int row = rowb + r;
                if (row < n) {
                    float v = acc[mf][nf][r] + bv;
                    if (col < CSPLIT)
                        Y1[(size_t)row * ldy1 + col] = v;
                    else
                        Y2[(size_t)row * ldy2 + (col - CSPLIT)] = v;
                }
            }
        }
    }
}

// ---------------------------------------------------------------------------
// CSR build: histogram -> block sums -> scan sums -> per-block scan -> fill
// ---------------------------------------------------------------------------
__global__ void deg_kernel(const int* __restrict__ ei, int* __restrict__ deg)
{
    int t = blockIdx.x * blockDim.x + threadIdx.x;
    if (t < NE) atomicAdd(&deg[ei[NE + t]], 1);   // dst of edge t
}

__global__ void block_sum_kernel(const int* __restrict__ deg, int* __restrict__ bsum)
{
    int node = blockIdx.x * 256 + threadIdx.x;
    int v = (node < NN) ? deg[node] + 1 : 0;      // +1 = self loop
#pragma unroll
    for (int off = 32; off > 0; off >>= 1) v += __shfl_down(v, off);
    __shared__ int sh[4];
    if ((threadIdx.x & 63) == 0) sh[threadIdx.x >> 6] = v;
    __syncthreads();
    if (threadIdx.x == 0) bsum[blockIdx.x] = sh[0] + sh[1] + sh[2] + sh[3];
}

__global__ void scan_sums_kernel(const int* __restrict__ bsum, int* __restrict__ bsumx,
                                 int* __restrict__ rowptr)
{
    if (threadIdx.x == 0) {
        int run = 0;
        for (int i = 0; i < NB; ++i) { bsumx[i] = run; run += bsum[i]; }
        rowptr[NN] = run;    // == EP
    }
}

__global__ void scan_blocks_kernel(const int* __restrict__ deg, const int* __restrict__ bsumx,
                                   int* __restrict__ rowptr, int* __restrict__ cursor)
{
    __shared__ int sh[256];
    int node = blockIdx.x * 256 + threadIdx.x;
    int v = (node < NN) ? deg[node] + 1 : 0;
    sh[threadIdx.x] = v;
    __syncthreads();
#pragma unroll
    for (int off = 1; off < 256; off <<= 1) {
        int tv = (threadIdx.x >= off) ? sh[threadIdx.x - off] : 0;
        __syncthreads();
        sh[threadIdx.x] += tv;
        __syncthreads();
    }
    if (node < NN) {
        int excl = bsumx[blockIdx.x] + sh[threadIdx.x] - v;
        rowptr[node] = excl;
        cursor[node] = excl;
    }
}

__global__ void fill_kernel(const int* __restrict__ ei, int* __restrict__ cursor,
                            int* __restrict__ csr_src)
{
    int t = blockIdx.x * blockDim.x + threadIdx.x;
    if (t >= EP) return;
    int s, d;
    if (t < NE) { s = ei[t]; d = ei[NE + t]; }
    else        { s = d = t - NE; }
    int pos = atomicAdd(&cursor[d], 1);
    csr_src[pos] = s;
}

// ---------------------------------------------------------------------------
// Softmax stats + normalized edge weights. ONE THREAD PER NODE.
// ---------------------------------------------------------------------------
template<int HH>
__global__ __launch_bounds__(256)
void attn_weights_kernel(const int* __restrict__ rowptr, const int* __restrict__ csr_src,
                         const float* __restrict__ als, const float* __restrict__ ald,
                         float* __restrict__ wq, int n)
{
    int node = blockIdx.x * 256 + threadIdx.x;
    if (node >= n) return;
    const int e0 = rowptr[node], e1 = rowptr[node + 1];
    float aldv[HH], m[HH], d[HH];
#pragma unroll
    for (int h = 0; h < HH; ++h) { m[h] = -1e30f; d[h] = 0.f; }
    if constexpr (HH == 4) {
        float4 a = *(const float4*)&ald[(size_t)node * 4];
        aldv[0] = a.x; aldv[1] = a.y; aldv[2] = a.z; aldv[3] = a.w;
    } else {
        aldv[0] = ald[node];
    }
    for (int e = e0; e < e1; ++e) {
        int s = csr_src[e];
        float av[HH];
        if constexpr (HH == 4) {
            float4 a = *(const float4*)&als[(size_t)s * 4];
            av[0] = a.x; av[1] = a.y; av[2] = a.z; av[3] = a.w;
        } else {
            av[0] = als[s];
        }
#pragma unroll
        for (int h = 0; h < HH; ++h) {
            float sc = leaky(av[h] + aldv[h]);
            float nm = fmaxf(m[h], sc);
            d[h] = d[h] * __expf(m[h] - nm) + __expf(sc - nm);
            m[h] = nm;
        }
    }
#pragma unroll
    for (int h = 0; h < HH; ++h) d[h] = 1.f / d[h];
    for (int e = e0; e < e1; ++e) {
        int s = csr_src[e];
        float av[HH];
        if constexpr (HH == 4) {
            float4 a = *(const float4*)&als[(size_t)s * 4];
            av[0] = a.x; av[1] = a.y; av[2] = a.z; av[3] = a.w;
        } else {
            av[0] = als[s];
        }
        float wv[HH];
#pragma unroll
        for (int h = 0; h < HH; ++h)
            wv[h] = __expf(leaky(av[h] + aldv[h]) - m[h]) * d[h];
        if constexpr (HH == 4) {
            float4 o; o.x = wv[0]; o.y = wv[1]; o.z = wv[2]; o.w = wv[3];
            *(float4*)&wq[(size_t)e * 4] = o;
        } else {
            wq[e] = wv[0];
        }
    }
}

// ---------------------------------------------------------------------------
// Weighted gather-SpMM + fused epilogue. ONE WAVE PER NODE, lane = channel
// pair. Output written as pre-split hi/lo bf16 (consumed by downstream
// ASPLIT GEMMs). Residual either f32 or split (RESSPLIT).
// ---------------------------------------------------------------------------
template<int HH, int CC, bool DOELU, bool RESSPLIT>
__global__ __launch_bounds__(256)
void spmm_kernel(const int* __restrict__ rowptr, const int* __restrict__ csr_src,
                 const float* __restrict__ xh, const float* __restrict__ wq,
                 const float* __restrict__ b,
                 const float* __restrict__ resf,
                 const ushort* __restrict__ resh, const ushort* __restrict__ resl,
                 ushort* __restrict__ outh, ushort* __restrict__ outl, int n)
{
    constexpr int HCL = HH * CC;
    constexpr int CPL = HCL / 64;                 // channels per lane (2 or 1)
    const int l = threadIdx.x & 63;
    const int node = blockIdx.x * 4 + (threadIdx.x >> 6);
    if (node >= n) return;
    const int c = l * CPL;
    const int h = c / CC;
    const int e0 = rowptr[node], e1 = rowptr[node + 1];

    float a0[CPL], a1[CPL];
#pragma unroll
    for (int j = 0; j < CPL; ++j) { a0[j] = 0.f; a1[j] = 0.f; }

    int e = e0;
    for (; e + 1 < e1; e += 2) {
        int s0 = csr_src[e], s1 = csr_src[e + 1];
        float w0 = wq[(size_t)e * HH + h];
        float w1 = wq[(size_t)(e + 1) * HH + h];
        if constexpr (CPL == 2) {
            float2 x0 = *(const float2*)&xh[(size_t)s0 * HCL + c];
            float2 x1 = *(const float2*)&xh[(size_t)s1 * HCL + c];
            a0[0] = fmaf(w0, x0.x, a0[0]); a0[1] = fmaf(w0, x0.y, a0[1]);
            a1[0] = fmaf(w1, x1.x, a1[0]); a1[1] = fmaf(w1, x1.y, a1[1]);
        } else {
            a0[0] = fmaf(w0, xh[(size_t)s0 * HCL + c], a0[0]);
            a1[0] = fmaf(w1, xh[(size_t)s1 * HCL + c], a1[0]);
        }
    }
    if (e < e1) {
        int s0 = csr_src[e];
        float w0 = wq[(size_t)e * HH + h];
        if constexpr (CPL == 2) {
            float2 x0 = *(const float2*)&xh[(size_t)s0 * HCL + c];
            a0[0] = fmaf(w0, x0.x, a0[0]); a0[1] = fmaf(w0, x0.y, a0[1]);
        } else {
            a0[0] = fmaf(w0, xh[(size_t)s0 * HCL + c], a0[0]);
        }
    }

#pragma unroll
    for (int j = 0; j < CPL; ++j) {
        size_t idx = (size_t)node * HCL + c + j;
        float rv;
        if constexpr (RESSPLIT) rv = bf2f(resh[idx]) + bf2f(resl[idx]);
        else                    rv = resf[idx];
        float v = a0[j] + a1[j] + b[c + j] + rv;
        if (DOELU) v = v > 0.f ? v : (__expf(v) - 1.f);
        ushort hh = f2bf(v);
        outh[idx] = hh;
        outl[idx] = f2bf(v - bf2f(hh));
    }
}

// ---------------------------------------------------------------------------
extern "C" void kernel_launch(void* const* d_in, const int* in_sizes, int n_in,
                              void* d_out, int out_size, void* d_ws, size_t ws_size,
                              hipStream_t stream)
{
    const float* x    = (const float*)d_in[0];
    const int*   ei   = (const int*)d_in[1];
    const float* W0   = (const float*)d_in[2];
    const float* b0   = (const float*)d_in[3];
    const float* as0  = (const float*)d_in[4];
    const float* ad0  = (const float*)d_in[5];
    const float* W1   = (const float*)d_in[6];
    const float* b1   = (const float*)d_in[7];
    const float* as1  = (const float*)d_in[8];
    const float* ad1  = (const float*)d_in[9];
    const float* W2   = (const float*)d_in[10];
    const float* b2   = (const float*)d_in[11];
    const float* as2  = (const float*)d_in[12];
    const float* ad2  = (const float*)d_in[13];
    const float* sk0W = (const float*)d_in[14];
    const float* sk0b = (const float*)d_in[15];
    const float* sk2W = (const float*)d_in[16];
    const float* sk2b = (const float*)d_in[17];
    const float* jkW  = (const float*)d_in[18];
    const float* jkb  = (const float*)d_in[19];
    float* out = (float*)d_out;

    float* ws = (float*)d_ws;
    size_t off = 0;
    float* s_xh  = ws + off; off += (size_t)NN * 128;   // GEMM xh out (f32 gather src)
    float* s_r0  = ws + off; off += (size_t)NN * 128;   // res0 f32; reused as res2
    float* s_als = ws + off; off += (size_t)NN * 4;
    float* s_ald = ws + off; off += (size_t)NN * 4;
    float* f_wq  = ws + off; off += (size_t)EP * 4;
    // split-bf16 activations (hi/lo), consumed by ASPLIT GEMMs
    ushort* u_x0h = (ushort*)(ws + off); off += (size_t)NN * 64;   // [NN][128] u16
    ushort* u_x0l = (ushort*)(ws + off); off += (size_t)NN * 64;
    ushort* u_x1h = (ushort*)(ws + off); off += (size_t)NN * 64;
    ushort* u_x1l = (ushort*)(ws + off); off += (size_t)NN * 64;
    ushort* u_h2h = (ushort*)(ws + off); off += (size_t)NN * 32;   // [NN][64] u16
    ushort* u_h2l = (ushort*)(ws + off); off += (size_t)NN * 32;
    int* i_deg    = (int*)(ws + off); off += NN;
    int* i_rowptr = (int*)(ws + off); off += NN + 1;
    int* i_cursor = (int*)(ws + off); off += NN;
    int* i_csrsrc = (int*)(ws + off); off += EP;
    int* i_bsum   = (int*)(ws + off); off += NB;
    int* i_bsumx  = (int*)(ws + off); off += NB;
    off = (off + 3) & ~(size_t)3;     // 16B-align the bf16 weight tiles
    ushort* wt0h = (ushort*)(ws + off); off += 32768;   // 8*256*32 u16
    ushort* wt0l = (ushort*)(ws + off); off += 32768;
    ushort* wt1h = (ushort*)(ws + off); off += 8192;    // 4*128*32 u16
    ushort* wt1l = (ushort*)(ws + off); off += 8192;
    ushort* wt2h = (ushort*)(ws + off); off += 8192;    // 4*128*32 u16
    ushort* wt2l = (ushort*)(ws + off); off += 8192;
    ushort* wtjh = (ushort*)(ws + off); off += 10240;   // 10*64*32 u16
    ushort* wtjl = (ushort*)(ws + off); off += 10240;

    const int GM = (NN + 127) / 128;    // 782 row blocks
    const int GN = (NN + 255) / 256;    // node-thread blocks
    const int GS = (NN + 3) / 4;        // node-wave blocks
    constexpr int BIG = 1 << 30;

    // ======================= CSR build (shared by all 3 layers) ==========
    hipMemsetAsync(i_deg, 0, (size_t)NN * sizeof(int), stream);
    deg_kernel<<<(NE + 255) / 256, 256, 0, stream>>>(ei, i_deg);
    block_sum_kernel<<<NB, 256, 0, stream>>>(i_deg, i_bsum);
    scan_sums_kernel<<<1, 64, 0, stream>>>(i_bsum, i_bsumx, i_rowptr);
    scan_blocks_kernel<<<NB, 256, 0, stream>>>(i_deg, i_bsumx, i_rowptr, i_cursor);
    fill_kernel<<<(EP + 255) / 256, 256, 0, stream>>>(ei, i_cursor, i_csrsrc);

    // ======================= weight pre-tiling (split bf16) ==============
    pretile_kernel<<<256, 256, 0, stream>>>(W0, sk0W, 256, 128, 256, wt0h, wt0l);
    pretile_kernel<<<64,  256, 0, stream>>>(W1, nullptr, 128, 128, 128, wt1h, wt1l);
    pretile_kernel<<<64,  256, 0, stream>>>(W2, sk2W, 128, 64, 128, wt2h, wt2l);
    pretile_kernel<<<80,  256, 0, stream>>>(jkW, nullptr, 320, 64, 64, wtjh, wtjl);

    // ======= layer 0: fused [xh0 | res0] = x @ [W0 | sk0W] (K=256, N=256)
    gemm_mfma<256, 256, 128, 256, 256, 128, 128, 4, 32, 128, false>
        <<<dim3(GM, 2), 256, 0, stream>>>(
        x, nullptr, nullptr, nullptr, nullptr, nullptr, 256, 0, 0,
        wt0h, wt0l, sk0b,
        s_xh, s_r0, 128, 128, s_als, s_ald, as0, ad0, NN);
    attn_weights_kernel<4><<<GN, 256, 0, stream>>>(
        i_rowptr, i_csrsrc, s_als, s_ald, f_wq, NN);
    spmm_kernel<4, 32, true, false><<<GS, 256, 0, stream>>>(
        i_rowptr, i_csrsrc, s_xh, f_wq, b0, s_r0, nullptr, nullptr,
        u_x0h, u_x0l, NN);

    // ======= layer 1: xh1 = x0 @ W1 (K=128, N=128; split-bf16 A input)
    gemm_mfma<128, 128, 128, 128, 128, 128, BIG, 4, 32, 128, true>
        <<<dim3(GM, 1), 256, 0, stream>>>(
        u_x0h, u_x0l, nullptr, nullptr, nullptr, nullptr, 128, 0, 0,
        wt1h, wt1l, nullptr,
        s_xh, nullptr, 128, 0, s_als, s_ald, as1, ad1, NN);
    attn_weights_kernel<4><<<GN, 256, 0, stream>>>(
        i_rowptr, i_csrsrc, s_als, s_ald, f_wq, NN);
    spmm_kernel<4, 32, true, true><<<GS, 256, 0, stream>>>(
        i_rowptr, i_csrsrc, s_xh, f_wq, b1, nullptr, u_x0h, u_x0l,
        u_x1h, u_x1l, NN);

    // ======= layer 2: fused [xh2 | res2] = x1 @ [W2 | sk2W] (K=128, N=128)
    gemm_mfma<128, 128, 128, 128, 128, 64, 64, 1, 64, 64, true>
        <<<dim3(GM, 1), 256, 0, stream>>>(
        u_x1h, u_x1l, nullptr, nullptr, nullptr, nullptr, 128, 0, 0,
        wt2h, wt2l, sk2b,
        s_xh, s_r0, 64, 64, s_als, s_ald, as2, ad2, NN);
    attn_weights_kernel<1><<<GN, 256, 0, stream>>>(
        i_rowptr, i_csrsrc, s_als, s_ald, f_wq, NN);
    spmm_kernel<1, 64, false, false><<<GS, 256, 0, stream>>>(
        i_rowptr, i_csrsrc, s_xh, f_wq, b2, s_r0, nullptr, nullptr,
        u_h2h, u_h2l, NN);

    // ======= JumpingKnowledge: out = [x0|x1|h2] @ jkW + jkb (K=320, N=64)
    gemm_mfma<320, 64, 64, 128, 256, 64, 0, 0, 16, 0, true>
        <<<dim3(GM, 1), 256, 0, stream>>>(
        u_x0h, u_x0l, u_x1h, u_x1l, u_h2h, u_h2l, 128, 128, 64,
        wtjh, wtjl, jkb,
        out, nullptr, 64, 0, nullptr, nullptr, nullptr, nullptr, NN);
}